// Round 9
// baseline (178.620 us; speedup 1.0000x reference)
//
#include <hip/hip_runtime.h>
#include <cstdint>

// GRU RNN fused persistent kernel for MI355X (gfx950).  T=256,B=4096,D=128,H=16.
// Round 9: R8 bug-fixed — 4 compute + 12 loader waves, CORRECT 32-segment split.
//
//  R8 crashed on a segment-count bug (assigned 64 segment ids to a 32-segment
//  chunk -> LDS overrun). Chunk = 4 steps x 16 elems x 128 f32 = 32 KB = 32
//  x 1KB segments (64 rows x 512B). Correct split for 12 loaders:
//  loaders 0-7: 3 A-segments; loaders 8-11: 2 A-segments + mask block.
//  Uniform G=3 vmem ops per loader per chunk.
//
//  - grid 256 x 1024. Waves 0-3 compute (identical to R7-passing: MFMA gx ->
//    register scan via bpermute, zero vmem ops). Waves 4-15: loaders.
//  - Handshake: ONE s_barrier per chunk; loaders verify chunk c+1 landed
//    before barrier(c+1) with counted vmcnt(2G)=6 steady, 3 / 0 tail only.
//    Ring safety: compute reads slot c&3; loaders write (c+3)&3 == (c-1)&3,
//    freed at barrier(c). Identical protocol to R7.
//  - Ring As[4] (128 KB) + Whi/Wlo planes (24.75 KB, pad 132) + mask ring
//    (4 KB) = 156.75 KB LDS, 1 block/CU (same as passing R7).
//  - MFMA: elem-major A rows, 16B-granule XOR swizzle both-sides, bf16 hi/lo
//    3-pass split (hh+lh+hl) ~f32-exact; D-frag lands in the scan lanes.
//  - Scan: packed-f32 dots (v_pk_fma) + 16 bpermute broadcasts, no barriers.

#define TT 256
#define BB 4096
#define DD 128
#define HH 16
#define TC 4
#define NCH (TT / TC)  // 64
#define EPB 16
#define WPAD 132       // shorts per W-plane row (264B stride -> 2-way banks)

typedef float    f32x2  __attribute__((ext_vector_type(2)));
typedef float    f32x4  __attribute__((ext_vector_type(4)));
typedef short    bf16x8 __attribute__((ext_vector_type(8)));
typedef uint32_t u32x4  __attribute__((ext_vector_type(4)));

__device__ __forceinline__ void split8(const f32x4& x0, const f32x4& x1,
                                       bf16x8& hi8, bf16x8& lo8) {
  float xs[8] = {x0.x, x0.y, x0.z, x0.w, x1.x, x1.y, x1.z, x1.w};
  uint32_t hiw[4], low[4];
#pragma unroll
  for (int j = 0; j < 4; ++j) {
    uint32_t e0 = __float_as_uint(xs[2 * j]);
    uint32_t e1 = __float_as_uint(xs[2 * j + 1]);
    uint32_t h0 = e0 & 0xFFFF0000u, h1 = e1 & 0xFFFF0000u;
    hiw[j] = (h0 >> 16) | h1;
    float l0 = xs[2 * j] - __uint_as_float(h0);
    float l1 = xs[2 * j + 1] - __uint_as_float(h1);
    low[j] = (__float_as_uint(l0) >> 16) | (__float_as_uint(l1) & 0xFFFF0000u);
  }
  hi8 = __builtin_bit_cast(bf16x8, (u32x4){hiw[0], hiw[1], hiw[2], hiw[3]});
  lo8 = __builtin_bit_cast(bf16x8, (u32x4){low[0], low[1], low[2], low[3]});
}

__global__ __launch_bounds__(1024, 1) void gru_fused(
    const float* __restrict__ feat, const float* __restrict__ bmask,
    const float* __restrict__ hx0, const float* __restrict__ Wih,
    const float* __restrict__ Whh, const float* __restrict__ bih,
    const float* __restrict__ bhh, float* __restrict__ out) {
  __shared__ __align__(16) float As[4][TC * EPB * DD];      // 128 KB ring
  __shared__ __align__(16) unsigned short Whi[48 * WPAD];   // 12.375 KB
  __shared__ __align__(16) unsigned short Wlo[48 * WPAD];   // 12.375 KB
  __shared__ __align__(16) float ms[4][256];                // 4 KB mask ring

  const int tid  = threadIdx.x;
  const int lane = tid & 63;
  const int wv   = tid >> 6;  // 0-3 compute, 4-15 loader
  const int b0   = blockIdx.x * EPB;

  if (wv >= 4) {
    // ==================== loader waves (12 read streams) ====================
    const int hw = wv - 4;  // 0..11
    auto seg_load = [&](int s, char* AsB, const char* base) {
      int row = 2 * s + (lane >> 5);  // staged row 0..63 = e*4 + tq
      int e = row >> 2, tq = row & 3;
      int inrow = (lane & 31) << 4;
      int off = e * (DD * 4) + (inrow ^ ((row & 7) << 4));  // pre-swizzled
      const char* g = base + (size_t)tq * ((size_t)BB * DD * 4) + off;
      __builtin_amdgcn_global_load_lds(
          (const __attribute__((address_space(1))) void*)g,
          (__attribute__((address_space(3))) void*)(AsB + s * 1024), 16, 0, 0);
    };
    auto stage = [&](int c) {
      char* AsB = (char*)As[c & 3];
      const char* base =
          (const char*)(feat + (size_t)c * TC * BB * DD + (size_t)b0 * DD);
      if (hw < 8) {
        // 3 A-segments: s = hw*3 + k, k<3 -> 0..23
#pragma unroll
        for (int k = 0; k < 3; ++k) seg_load(hw * 3 + k, AsB, base);
      } else {
        // 2 A-segments: s = 24 + (hw-8)*2 + k -> 24..31, plus mask block
#pragma unroll
        for (int k = 0; k < 2; ++k) seg_load(24 + (hw - 8) * 2 + k, AsB, base);
        {  // mask block for compute wave hw-8 (lanes>=16 harmless dups)
          int tq = lane & 3, el = (lane >> 2) & 3;
          const char* g = (const char*)(bmask + (size_t)(c * TC + tq) * BB +
                                        b0 + (hw - 8) * 4 + el);
          __builtin_amdgcn_global_load_lds(
              (const __attribute__((address_space(1))) void*)g,
              (__attribute__((address_space(3))) void*)((char*)ms[c & 3] +
                                                        (hw - 8) * 256),
              4, 0, 0);
        }
      }
    };
    stage(0);
    stage(1);
    stage(2);
    asm volatile("s_waitcnt vmcnt(6)" ::: "memory");  // chunk 0 landed
    for (int c = 0; c < NCH; ++c) {
      __builtin_amdgcn_s_barrier();  // chunk c landed; slot (c-1)&3 now free
      asm volatile("" ::: "memory");
      if (c + 3 < NCH) stage(c + 3);
      // guarantee chunk c+1 landed before barrier(c+1):
      if (c <= NCH - 4)      asm volatile("s_waitcnt vmcnt(6)" ::: "memory");
      else if (c == NCH - 3) asm volatile("s_waitcnt vmcnt(3)" ::: "memory");
      else if (c == NCH - 2) asm volatile("s_waitcnt vmcnt(0)" ::: "memory");
      asm volatile("" ::: "memory");
    }
    return;
  }

  // ======================= compute (scan) waves =======================
  const int li = lane & 15;    // MFMA row/col index == hidden unit si
  const int lq = lane >> 4;    // MFMA quarter == elem-within-wave
  const int si = li;
  const int se = wv * 4 + lq;  // this thread's batch elem (0..15)

  // prologue: W_ih -> bf16 hi/lo planes in LDS (4 compute waves = 256 threads)
  for (int idx = wv * 64 + lane; idx < 48 * DD; idx += 256) {
    int g = idx >> 7, k = idx & 127;
    float w = Wih[idx];
    uint32_t u = __float_as_uint(w);
    uint32_t hb = u & 0xFFFF0000u;       // trunc-to-bf16 (hi)
    float l = w - __uint_as_float(hb);   // exact residual
    Whi[g * WPAD + k] = (unsigned short)(hb >> 16);
    Wlo[g * WPAD + k] = (unsigned short)(__float_as_uint(l) >> 16);
  }

  // W_hh rows as float2 pairs (v_pk_fma_f32), biases, h init
  f32x2 whhA2[8], whhB2[8], whhC2[8];
#pragma unroll
  for (int k = 0; k < 8; ++k) {
    whhA2[k] = *(const f32x2*)&Whh[si * HH + 2 * k];
    whhB2[k] = *(const f32x2*)&Whh[(si + 16) * HH + 2 * k];
    whhC2[k] = *(const f32x2*)&Whh[(si + 32) * HH + 2 * k];
  }
  const float bhA = bhh[si], bhB = bhh[si + 16], bhC = bhh[si + 32];
  const float biA = bih[si], biB = bih[si + 16], biC = bih[si + 32];
  float h = hx0[(size_t)(b0 + se) * HH + si];

  const int pbase = (lane & 48) << 2;  // 16-lane group base for bpermute

  // W planes must be complete before barrier(0) makes them visible
  asm volatile("s_waitcnt lgkmcnt(0)" ::: "memory");

  for (int c = 0; c < NCH; ++c) {
    asm volatile("" ::: "memory");
    __builtin_amdgcn_s_barrier();  // chunk c landed (loader-verified)
    asm volatile("" ::: "memory");

    // masks for this chunk
    f32x4 mm = *(const f32x4*)((const char*)ms[c & 3] + wv * 256 + lq * 16);

    // ===== MFMA: gx for this wave's 4 elems x 4 steps, into registers =====
    const char* AsB = (const char*)As[c & 3];
    f32x4 acc0 = {0.f, 0.f, 0.f, 0.f};
    f32x4 acc1 = {0.f, 0.f, 0.f, 0.f};
    f32x4 acc2 = {0.f, 0.f, 0.f, 0.f};
#pragma unroll
    for (int ks = 0; ks < 4; ++ks) {
      // B fragments from LDS planes (row stride 264B -> 2-way banks, free)
      bf16x8 Bh0, Bl0, Bh1, Bl1, Bh2, Bl2;
      {
        int wb0 = (li) * (WPAD * 2) + ks * 64 + lq * 16;
        int wb1 = (16 + li) * (WPAD * 2) + ks * 64 + lq * 16;
        int wb2 = (32 + li) * (WPAD * 2) + ks * 64 + lq * 16;
        Bh0 = *(const bf16x8*)((const char*)Whi + wb0);
        Bl0 = *(const bf16x8*)((const char*)Wlo + wb0);
        Bh1 = *(const bf16x8*)((const char*)Whi + wb1);
        Bl1 = *(const bf16x8*)((const char*)Wlo + wb1);
        Bh2 = *(const bf16x8*)((const char*)Whi + wb2);
        Bl2 = *(const bf16x8*)((const char*)Wlo + wb2);
      }
      int row = wv * 16 + li;
      int a0o = row * 512 + ((ks * 128 + lq * 32) ^ ((row & 7) << 4));
      f32x4 x0 = *(const f32x4*)(AsB + a0o);
      f32x4 x1 = *(const f32x4*)(AsB + (a0o ^ 16));
      bf16x8 Ah, Al;
      split8(x0, x1, Ah, Al);
      acc0 = __builtin_amdgcn_mfma_f32_16x16x32_bf16(Ah, Bh0, acc0, 0, 0, 0);
      acc0 = __builtin_amdgcn_mfma_f32_16x16x32_bf16(Al, Bh0, acc0, 0, 0, 0);
      acc0 = __builtin_amdgcn_mfma_f32_16x16x32_bf16(Ah, Bl0, acc0, 0, 0, 0);
      acc1 = __builtin_amdgcn_mfma_f32_16x16x32_bf16(Ah, Bh1, acc1, 0, 0, 0);
      acc1 = __builtin_amdgcn_mfma_f32_16x16x32_bf16(Al, Bh1, acc1, 0, 0, 0);
      acc1 = __builtin_amdgcn_mfma_f32_16x16x32_bf16(Ah, Bl1, acc1, 0, 0, 0);
      acc2 = __builtin_amdgcn_mfma_f32_16x16x32_bf16(Ah, Bh2, acc2, 0, 0, 0);
      acc2 = __builtin_amdgcn_mfma_f32_16x16x32_bf16(Al, Bh2, acc2, 0, 0, 0);
      acc2 = __builtin_amdgcn_mfma_f32_16x16x32_bf16(Ah, Bl2, acc2, 0, 0, 0);
    }

    // ===== scan: 4 steps, registers + bpermute + packed-f32 dots =====
#pragma unroll
    for (int tq = 0; tq < 4; ++tq) {
      float f = 1.0f - mm[tq];
      f32x2 dA = {0.f, 0.f}, dB = {0.f, 0.f}, dC = {0.f, 0.f};
#pragma unroll
      for (int k = 0; k < 8; ++k) {
        float hx = __uint_as_float((uint32_t)__builtin_amdgcn_ds_bpermute(
            pbase + 8 * k, (int)__float_as_uint(h)));
        float hy = __uint_as_float((uint32_t)__builtin_amdgcn_ds_bpermute(
            pbase + 8 * k + 4, (int)__float_as_uint(h)));
        f32x2 hp = {hx, hy};
        dA = __builtin_elementwise_fma(whhA2[k], hp, dA);
        dB = __builtin_elementwise_fma(whhB2[k], hp, dB);
        dC = __builtin_elementwise_fma(whhC2[k], hp, dC);
      }
      float d0 = dA.x + dA.y;
      float d1 = dB.x + dB.y;
      float d2 = dC.x + dC.y;
      float g0 = acc0[tq] + biA;
      float g1 = acc1[tq] + biB;
      float g2 = acc2[tq] + biC;
      float r = 1.0f / (1.0f + __expf(-(g0 + f * d0 + bhA)));
      float z = 1.0f / (1.0f + __expf(-(g1 + f * d1 + bhB)));
      float a = g2 + r * (f * d2 + bhC);
      float n = 2.0f / (1.0f + __expf(-2.0f * a)) - 1.0f;  // tanh(a)
      float hm = f * h;
      h = n + z * (hm - n);  // (1-z)*n + z*h'
      out[((size_t)(c * TC + tq) * BB + b0 + se) * HH + si] = h;
    }
  }
}

extern "C" void kernel_launch(void* const* d_in, const int* in_sizes, int n_in,
                              void* d_out, int out_size, void* d_ws,
                              size_t ws_size, hipStream_t stream) {
  const float* feat  = (const float*)d_in[0];
  const float* bmask = (const float*)d_in[1];
  const float* hx0   = (const float*)d_in[2];
  const float* Wih   = (const float*)d_in[3];
  const float* Whh   = (const float*)d_in[4];
  const float* bih   = (const float*)d_in[5];
  const float* bhh   = (const float*)d_in[6];
  float* out = (float*)d_out;
  gru_fused<<<dim3(BB / EPB), dim3(1024), 0, stream>>>(feat, bmask, hx0, Wih,
                                                       Whh, bih, bhh, out);
}

// Round 10
// 154.456 us; speedup vs baseline: 1.1564x; 1.1564x over previous
//
#include <hip/hip_runtime.h>
#include <cstdint>

// GRU RNN fused persistent kernel for MI355X (gfx950).  T=256,B=4096,D=128,H=16.
// Round 10: restore of the R7 kernel (measured best: 156.1 us).
//
//  Evidence across R1-R9: chip-wide L2-miss READ delivery caps at ~3.3 TB/s
//  (m13 copy = 3.15 TB/s/direction; fill kernel = 6.9 TB/s pure writes; R7
//  sustained 3.28 TB/s reads; 12 loader waves (R9) regressed via barrier
//  overhead). Read-wall floor for this op = 516 MB / ~3.35 TB/s ~= 154 us;
//  R7 = 156.1 us ~= 98.5% of the wall.
//
//  - grid 256 x 768 threads. Waves 0-3 compute (4 elems each: MFMA gx ->
//    register scan via bpermute, zero vmem waits). Waves 4-11: loaders, each
//    stages 4 KB/chunk of the A-ring via global_load_lds; loaders 0-3 also
//    stage the mask block for compute wave hw.
//  - Ring As[4] (128 KB) + Whi/Wlo planes (24.75 KB, pad 132 -> 2-way reads)
//    + mask ring (4 KB) = 156.75 KB LDS, 1 block/CU.
//  - Handshake: ONE s_barrier per chunk; loaders verify chunk c+1 landed
//    before barrier(c+1) with per-wave counted vmcnt (2G steady, G/0 tail).
//    Ring safety: compute reads slot c&3, loaders write (c+3)&3 == (c-1)&3.
//  - MFMA: elem-major A rows, 16B-granule XOR swizzle both-sides, bf16 hi/lo
//    3-pass split (hh+lh+hl) ~f32-exact. D-frag lands in the scan lanes.
//  - Scan: packed-f32 dots (v_pk_fma) + 16 bpermute broadcasts, no barriers.

#define TT 256
#define BB 4096
#define DD 128
#define HH 16
#define TC 4
#define NCH (TT / TC)  // 64
#define EPB 16
#define WPAD 132       // shorts per W-plane row (264B stride -> 2-way banks)

typedef float    f32x2  __attribute__((ext_vector_type(2)));
typedef float    f32x4  __attribute__((ext_vector_type(4)));
typedef short    bf16x8 __attribute__((ext_vector_type(8)));
typedef uint32_t u32x4  __attribute__((ext_vector_type(4)));

__device__ __forceinline__ void split8(const f32x4& x0, const f32x4& x1,
                                       bf16x8& hi8, bf16x8& lo8) {
  float xs[8] = {x0.x, x0.y, x0.z, x0.w, x1.x, x1.y, x1.z, x1.w};
  uint32_t hiw[4], low[4];
#pragma unroll
  for (int j = 0; j < 4; ++j) {
    uint32_t e0 = __float_as_uint(xs[2 * j]);
    uint32_t e1 = __float_as_uint(xs[2 * j + 1]);
    uint32_t h0 = e0 & 0xFFFF0000u, h1 = e1 & 0xFFFF0000u;
    hiw[j] = (h0 >> 16) | h1;
    float l0 = xs[2 * j] - __uint_as_float(h0);
    float l1 = xs[2 * j + 1] - __uint_as_float(h1);
    low[j] = (__float_as_uint(l0) >> 16) | (__float_as_uint(l1) & 0xFFFF0000u);
  }
  hi8 = __builtin_bit_cast(bf16x8, (u32x4){hiw[0], hiw[1], hiw[2], hiw[3]});
  lo8 = __builtin_bit_cast(bf16x8, (u32x4){low[0], low[1], low[2], low[3]});
}

__global__ __launch_bounds__(768, 1) void gru_fused(
    const float* __restrict__ feat, const float* __restrict__ bmask,
    const float* __restrict__ hx0, const float* __restrict__ Wih,
    const float* __restrict__ Whh, const float* __restrict__ bih,
    const float* __restrict__ bhh, float* __restrict__ out) {
  __shared__ __align__(16) float As[4][TC * EPB * DD];      // 128 KB ring
  __shared__ __align__(16) unsigned short Whi[48 * WPAD];   // 12.375 KB
  __shared__ __align__(16) unsigned short Wlo[48 * WPAD];   // 12.375 KB
  __shared__ __align__(16) float ms[4][256];                // 4 KB mask ring

  const int tid  = threadIdx.x;
  const int lane = tid & 63;
  const int wv   = tid >> 6;  // 0-3 compute, 4-11 loader
  const int b0   = blockIdx.x * EPB;

  if (wv >= 4) {
    // ===================== loader waves (8 read streams) =====================
    const int hw = wv - 4;  // 0..7
    auto stage = [&](int c) {
      char* AsB = (char*)As[c & 3];
      const char* base =
          (const char*)(feat + (size_t)c * TC * BB * DD + (size_t)b0 * DD);
#pragma unroll
      for (int k = 0; k < 4; ++k) {
        int s = hw * 4 + k;             // 1KB segment (wave-uniform)
        int row = 2 * s + (lane >> 5);  // staged row 0..63 = e*4 + tq
        int e = row >> 2, tq = row & 3;
        int inrow = (lane & 31) << 4;
        int off = e * (DD * 4) + (inrow ^ ((row & 7) << 4));  // pre-swizzled
        const char* g = base + (size_t)tq * ((size_t)BB * DD * 4) + off;
        __builtin_amdgcn_global_load_lds(
            (const __attribute__((address_space(1))) void*)g,
            (__attribute__((address_space(3))) void*)(AsB + s * 1024), 16, 0, 0);
      }
      if (hw < 4) {  // mask block for compute wave hw (lanes>=16 harmless dups)
        int tq = lane & 3, el = (lane >> 2) & 3;
        const char* g = (const char*)(bmask + (size_t)(c * TC + tq) * BB + b0 +
                                      hw * 4 + el);
        __builtin_amdgcn_global_load_lds(
            (const __attribute__((address_space(1))) void*)g,
            (__attribute__((address_space(3))) void*)((char*)ms[c & 3] +
                                                      hw * 256),
            4, 0, 0);
      }
    };
    stage(0);
    stage(1);
    stage(2);
    if (hw < 4) asm volatile("s_waitcnt vmcnt(10)" ::: "memory");
    else        asm volatile("s_waitcnt vmcnt(8)" ::: "memory");
    for (int c = 0; c < NCH; ++c) {
      __builtin_amdgcn_s_barrier();  // chunk c landed; slot (c-1)&3 now free
      asm volatile("" ::: "memory");
      if (c + 3 < NCH) stage(c + 3);
      // guarantee chunk c+1 landed before barrier(c+1):
      if (c <= NCH - 4) {
        if (hw < 4) asm volatile("s_waitcnt vmcnt(10)" ::: "memory");
        else        asm volatile("s_waitcnt vmcnt(8)" ::: "memory");
      } else if (c == NCH - 3) {
        if (hw < 4) asm volatile("s_waitcnt vmcnt(5)" ::: "memory");
        else        asm volatile("s_waitcnt vmcnt(4)" ::: "memory");
      } else if (c == NCH - 2) {
        asm volatile("s_waitcnt vmcnt(0)" ::: "memory");
      }
      asm volatile("" ::: "memory");
    }
    return;
  }

  // ======================= compute (scan) waves =======================
  const int li = lane & 15;    // MFMA row/col index == hidden unit si
  const int lq = lane >> 4;    // MFMA quarter == elem-within-wave
  const int si = li;
  const int se = wv * 4 + lq;  // this thread's batch elem (0..15)

  // prologue: W_ih -> bf16 hi/lo planes in LDS (4 compute waves = 256 threads)
  for (int idx = wv * 64 + lane; idx < 48 * DD; idx += 256) {
    int g = idx >> 7, k = idx & 127;
    float w = Wih[idx];
    uint32_t u = __float_as_uint(w);
    uint32_t hb = u & 0xFFFF0000u;       // trunc-to-bf16 (hi)
    float l = w - __uint_as_float(hb);   // exact residual
    Whi[g * WPAD + k] = (unsigned short)(hb >> 16);
    Wlo[g * WPAD + k] = (unsigned short)(__float_as_uint(l) >> 16);
  }

  // W_hh rows as float2 pairs (v_pk_fma_f32), biases, h init
  f32x2 whhA2[8], whhB2[8], whhC2[8];
#pragma unroll
  for (int k = 0; k < 8; ++k) {
    whhA2[k] = *(const f32x2*)&Whh[si * HH + 2 * k];
    whhB2[k] = *(const f32x2*)&Whh[(si + 16) * HH + 2 * k];
    whhC2[k] = *(const f32x2*)&Whh[(si + 32) * HH + 2 * k];
  }
  const float bhA = bhh[si], bhB = bhh[si + 16], bhC = bhh[si + 32];
  const float biA = bih[si], biB = bih[si + 16], biC = bih[si + 32];
  float h = hx0[(size_t)(b0 + se) * HH + si];

  const int pbase = (lane & 48) << 2;  // 16-lane group base for bpermute

  // W planes must be complete before barrier(0) makes them visible
  asm volatile("s_waitcnt lgkmcnt(0)" ::: "memory");

  for (int c = 0; c < NCH; ++c) {
    asm volatile("" ::: "memory");
    __builtin_amdgcn_s_barrier();  // chunk c landed (loader-verified)
    asm volatile("" ::: "memory");

    // masks for this chunk
    f32x4 mm = *(const f32x4*)((const char*)ms[c & 3] + wv * 256 + lq * 16);

    // ===== MFMA: gx for this wave's 4 elems x 4 steps, into registers =====
    const char* AsB = (const char*)As[c & 3];
    f32x4 acc0 = {0.f, 0.f, 0.f, 0.f};
    f32x4 acc1 = {0.f, 0.f, 0.f, 0.f};
    f32x4 acc2 = {0.f, 0.f, 0.f, 0.f};
#pragma unroll
    for (int ks = 0; ks < 4; ++ks) {
      // B fragments from LDS planes (row stride 264B -> 2-way banks, free)
      bf16x8 Bh0, Bl0, Bh1, Bl1, Bh2, Bl2;
      {
        int wb0 = (li)*(WPAD * 2) + ks * 64 + lq * 16;
        int wb1 = (16 + li) * (WPAD * 2) + ks * 64 + lq * 16;
        int wb2 = (32 + li) * (WPAD * 2) + ks * 64 + lq * 16;
        Bh0 = *(const bf16x8*)((const char*)Whi + wb0);
        Bl0 = *(const bf16x8*)((const char*)Wlo + wb0);
        Bh1 = *(const bf16x8*)((const char*)Whi + wb1);
        Bl1 = *(const bf16x8*)((const char*)Wlo + wb1);
        Bh2 = *(const bf16x8*)((const char*)Whi + wb2);
        Bl2 = *(const bf16x8*)((const char*)Wlo + wb2);
      }
      int row = wv * 16 + li;
      int a0o = row * 512 + ((ks * 128 + lq * 32) ^ ((row & 7) << 4));
      f32x4 x0 = *(const f32x4*)(AsB + a0o);
      f32x4 x1 = *(const f32x4*)(AsB + (a0o ^ 16));
      bf16x8 Ah, Al;
      split8(x0, x1, Ah, Al);
      acc0 = __builtin_amdgcn_mfma_f32_16x16x32_bf16(Ah, Bh0, acc0, 0, 0, 0);
      acc0 = __builtin_amdgcn_mfma_f32_16x16x32_bf16(Al, Bh0, acc0, 0, 0, 0);
      acc0 = __builtin_amdgcn_mfma_f32_16x16x32_bf16(Ah, Bl0, acc0, 0, 0, 0);
      acc1 = __builtin_amdgcn_mfma_f32_16x16x32_bf16(Ah, Bh1, acc1, 0, 0, 0);
      acc1 = __builtin_amdgcn_mfma_f32_16x16x32_bf16(Al, Bh1, acc1, 0, 0, 0);
      acc1 = __builtin_amdgcn_mfma_f32_16x16x32_bf16(Ah, Bl1, acc1, 0, 0, 0);
      acc2 = __builtin_amdgcn_mfma_f32_16x16x32_bf16(Ah, Bh2, acc2, 0, 0, 0);
      acc2 = __builtin_amdgcn_mfma_f32_16x16x32_bf16(Al, Bh2, acc2, 0, 0, 0);
      acc2 = __builtin_amdgcn_mfma_f32_16x16x32_bf16(Ah, Bl2, acc2, 0, 0, 0);
    }

    // ===== scan: 4 steps, registers + bpermute + packed-f32 dots =====
#pragma unroll
    for (int tq = 0; tq < 4; ++tq) {
      float f = 1.0f - mm[tq];
      f32x2 dA = {0.f, 0.f}, dB = {0.f, 0.f}, dC = {0.f, 0.f};
#pragma unroll
      for (int k = 0; k < 8; ++k) {
        float hx = __uint_as_float((uint32_t)__builtin_amdgcn_ds_bpermute(
            pbase + 8 * k, (int)__float_as_uint(h)));
        float hy = __uint_as_float((uint32_t)__builtin_amdgcn_ds_bpermute(
            pbase + 8 * k + 4, (int)__float_as_uint(h)));
        f32x2 hp = {hx, hy};
        dA = __builtin_elementwise_fma(whhA2[k], hp, dA);
        dB = __builtin_elementwise_fma(whhB2[k], hp, dB);
        dC = __builtin_elementwise_fma(whhC2[k], hp, dC);
      }
      float d0 = dA.x + dA.y;
      float d1 = dB.x + dB.y;
      float d2 = dC.x + dC.y;
      float g0 = acc0[tq] + biA;
      float g1 = acc1[tq] + biB;
      float g2 = acc2[tq] + biC;
      float r = 1.0f / (1.0f + __expf(-(g0 + f * d0 + bhA)));
      float z = 1.0f / (1.0f + __expf(-(g1 + f * d1 + bhB)));
      float a = g2 + r * (f * d2 + bhC);
      float n = 2.0f / (1.0f + __expf(-2.0f * a)) - 1.0f;  // tanh(a)
      float hm = f * h;
      h = n + z * (hm - n);  // (1-z)*n + z*h'
      out[((size_t)(c * TC + tq) * BB + b0 + se) * HH + si] = h;
    }
  }
}

extern "C" void kernel_launch(void* const* d_in, const int* in_sizes, int n_in,
                              void* d_out, int out_size, void* d_ws,
                              size_t ws_size, hipStream_t stream) {
  const float* feat  = (const float*)d_in[0];
  const float* bmask = (const float*)d_in[1];
  const float* hx0   = (const float*)d_in[2];
  const float* Wih   = (const float*)d_in[3];
  const float* Whh   = (const float*)d_in[4];
  const float* bih   = (const float*)d_in[5];
  const float* bhh   = (const float*)d_in[6];
  float* out = (float*)d_out;
  gru_fused<<<dim3(BB / EPB), dim3(768), 0, stream>>>(feat, bmask, hx0, Wih,
                                                      Whh, bih, bhh, out);
}